// Round 5
// baseline (193.911 us; speedup 1.0000x reference)
//
#include <hip/hip_runtime.h>

// NonLocalBlock: B=4, C=256, HID=128, N=64*64=4096, all-f32 in/out.
// Pipeline (bf16 MFMA 32x32x16, fp32 accum):
//   P1 k_prep_w : w_phi/theta/g/mask -> bf16, granule-swizzled (key o&15)
//   P2 k_prep_x : x -> xT[b][n][256] bf16 swizzled (key n&15); zero colsum
//   K1 k_proj   : phiT/thetaT[b][n][128] (SW16 key n&15), gbuf[b][c][m] (SW16 key c&15)
//   K2 k_colsum : colsum[b][m] = sum_n exp(S[n][m]); also zeroes O32
//   K2b k_scale_g: g[c][m] *= 1/colsum[m]
//   K3 k_attn   : O32[b][n][c] += sum_m exp(S[n][m]) * g'[c][m]
//                 theta in LDS (staged once), phi A-frags in registers from global
//                 (software-pipelined), Gs DMA overlapped with S phase, Ps packed
//                 b64 writes via operand-swapped S, ms-split x2 + atomics.
//   K4 k_mask   : out = w_mask @ O^T + x  (DMA A-stage, single K pass)
// Swizzle SW16 (128-col sections): sc = (c&~127)|((((c>>3)&15)^(key&15))<<3)|(c&7)
// ws: phiT(4M) thetaT(4M) gbuf(4M) colsum(64K) XO=xT|O32(8M, aliased) W(256K)

#define NB   4
#define CIN  256
#define HIDN 128
#define NPIX 4096

typedef __attribute__((ext_vector_type(8))) short short8;
typedef __attribute__((ext_vector_type(4))) float f32x4;
typedef __attribute__((ext_vector_type(16))) float f32x16;

__device__ __forceinline__ unsigned short f2bf(float f) {
    unsigned u = __builtin_bit_cast(unsigned, f);
    u += 0x7fffu + ((u >> 16) & 1u);          // RNE; inputs finite
    return (unsigned short)(u >> 16);
}
__device__ __forceinline__ unsigned f2bf2(float lo, float hi) {
    return (unsigned)f2bf(lo) | ((unsigned)f2bf(hi) << 16);
}
__device__ __forceinline__ float bf2f(unsigned short s) {
    return __builtin_bit_cast(float, (unsigned)s << 16);
}
// async global->LDS, 16B/lane; LDS dest = wave-uniform base + lane*16
__device__ __forceinline__ void cp16(void* lds, const void* g) {
    __builtin_amdgcn_global_load_lds(
        (const __attribute__((address_space(1))) unsigned int*)g,
        (__attribute__((address_space(3))) unsigned int*)lds, 16, 0, 0);
}

// ---------------------------------------------------------------- P1: W conversion
// 32 blocks: [0,8) w_phi, [8,16) w_theta, [16,24) w_g, [24,32) w_mask.
__global__ __launch_bounds__(256) void k_prep_w(
    const float* __restrict__ wp, const float* __restrict__ wt,
    const float* __restrict__ wg, const float* __restrict__ wm,
    unsigned short* __restrict__ Wp, unsigned short* __restrict__ Wt,
    unsigned short* __restrict__ Wg, unsigned short* __restrict__ Wm)
{
    const int which = blockIdx.x >> 3;
    const float* src = (which == 0) ? wp : (which == 1) ? wt : (which == 2) ? wg : wm;
    unsigned short* dst = (which == 0) ? Wp : (which == 1) ? Wt : (which == 2) ? Wg : Wm;
#pragma unroll
    for (int t = 0; t < 2; ++t) {
        const int gidx = ((blockIdx.x & 7) * 256 + threadIdx.x) * 2 + t;  // 4096 granules
        int o, srcc, dstc;
        if (which < 3) {                       // [128][256]
            o = gidx >> 5;
            const int gc = gidx & 31;
            const int sg = (gc & ~15) | ((gc & 15) ^ (o & 15));
            srcc = o * 256 + gc * 8; dstc = o * 256 + sg * 8;
        } else {                               // [256][128]
            o = gidx >> 4;
            const int gc = gidx & 15;
            const int sg = gc ^ (o & 15);
            srcc = o * 128 + gc * 8; dstc = o * 128 + sg * 8;
        }
        float4 a = *(const float4*)&src[srcc];
        float4 b = *(const float4*)&src[srcc + 4];
        uint4 v;
        v.x = f2bf2(a.x, a.y); v.y = f2bf2(a.z, a.w);
        v.z = f2bf2(b.x, b.y); v.w = f2bf2(b.z, b.w);
        *(uint4*)&dst[dstc] = v;
    }
}

// ---------------------------------------------------------------- P2: x -> xT bf16 swizzled
// grid (nt=64, ct=4, b=4). Tile [64 c][64 n]. Also zeroes colsum (ct==0 blocks).
__global__ __launch_bounds__(256) void k_prep_x(
    const float* __restrict__ x,
    unsigned short* __restrict__ xT,   // [B][N][256] SW16 key n&15
    float* __restrict__ colsum)
{
    const int nt = blockIdx.x, ct = blockIdx.y, b = blockIdx.z;
    const int tid = threadIdx.x;
    if (ct == 0 && tid < 64) colsum[(size_t)b * NPIX + nt * 64 + tid] = 0.f;

    __shared__ unsigned short Ls[64][66];
    {   // read x tile [64 c][64 n] coalesced, convert, store LDS
        const int c_loc = tid >> 2, n_seg = (tid & 3) * 16;
        const float* src = x + ((size_t)(b * CIN + ct * 64 + c_loc)) * NPIX + nt * 64 + n_seg;
#pragma unroll
        for (int j = 0; j < 8; ++j)
            *(unsigned*)&Ls[c_loc][n_seg + 2 * j] = f2bf2(src[2 * j], src[2 * j + 1]);
    }
    __syncthreads();
    {   // write xT rows: thread handles row n_loc, 16 c values (2 granules)
        const int n_loc = tid >> 2, c_seg = (tid & 3) * 16;
        const int n_glob = nt * 64 + n_loc;
        unsigned short tmp[16];
#pragma unroll
        for (int j = 0; j < 16; ++j) tmp[j] = Ls[c_seg + j][n_loc];
#pragma unroll
        for (int gr = 0; gr < 2; ++gr) {
            const int c_base = ct * 64 + c_seg + gr * 8;
            const int sec = c_base >> 7;
            const int sg = (((c_base >> 3) & 15) ^ (n_glob & 15));
            *(uint4*)&xT[((size_t)b * NPIX + n_glob) * CIN + sec * 128 + sg * 8] =
                *(uint4*)&tmp[gr * 8];
        }
    }
}

// ---------------------------------------------------------------- K1: projections (GEMM)
// grid (nt=64, ot=3, b=4) = 768 = 3/CU. Block tile [128 o][64 n], K=256 in 2 halves.
__global__ __launch_bounds__(256, 3) void k_proj(
    const unsigned short* __restrict__ Wp,   // [128][256] bf16 SW16 key o&15
    const unsigned short* __restrict__ Wt,
    const unsigned short* __restrict__ Wg,
    const unsigned short* __restrict__ xT,   // [B][N][256] SW16 key n&15
    unsigned short* __restrict__ phiT,       // [B][N][128] SW16 key n&15
    unsigned short* __restrict__ thetaT,
    unsigned short* __restrict__ gbuf)       // [B][128][N] SW16 key c&15
{
    const int nt = blockIdx.x, ot = blockIdx.y, b = blockIdx.z;
    const unsigned short* W = (ot == 0) ? Wp : (ot == 1) ? Wt : Wg;

    __shared__ alignas(16) unsigned short Aw[128][128];  // W k-half
    __shared__ alignas(16) unsigned short Bx[64][128];   // xT k-half

    const int tid = threadIdx.x;
    const int wave = tid >> 6, lane = tid & 63;
    const int oh = wave >> 1, nh = wave & 1;
    const int l31 = lane & 31, lh = lane >> 5;
    const int key = l31 & 15;

    f32x16 acc[2];
#pragma unroll
    for (int r = 0; r < 16; ++r) { acc[0][r] = 0.f; acc[1][r] = 0.f; }

    for (int kh = 0; kh < 2; ++kh) {
        __syncthreads();
#pragma unroll
        for (int i = 0; i < 8; ++i) {   // Aw: 128 rows x 128 shorts
            const int u = i * 256 + tid;
            cp16(&Aw[0][0] + u * 8, W + (u >> 4) * 256 + kh * 128 + (u & 15) * 8);
        }
#pragma unroll
        for (int i = 0; i < 4; ++i) {   // Bx: 64 rows x 128 shorts
            const int u = i * 256 + tid;
            cp16(&Bx[0][0] + u * 8,
                 xT + ((size_t)b * NPIX + nt * 64 + (u >> 4)) * CIN + kh * 128 + (u & 15) * 8);
        }
        __syncthreads();
#pragma unroll
        for (int ks = 0; ks < 8; ++ks) {
            const int g = ((ks * 2 + lh) ^ key) << 3;
            short8 bb = *(const short8*)&Bx[nh * 32 + l31][g];
#pragma unroll
            for (int t = 0; t < 2; ++t) {
                short8 a = *(const short8*)&Aw[oh * 64 + t * 32 + l31][g];
                acc[t] = __builtin_amdgcn_mfma_f32_32x32x16_bf16(a, bb, acc[t], 0, 0, 0);
            }
        }
    }

    const int n_glob = nt * 64 + nh * 32 + l31;
    if (ot < 2) {
        unsigned short* T = (ot == 0) ? phiT : thetaT;
#pragma unroll
        for (int t = 0; t < 2; ++t)
#pragma unroll
            for (int rg = 0; rg < 4; ++rg) {
                const int ob = oh * 64 + t * 32 + 8 * rg + 4 * lh;   // 4 consecutive o
                const int sc = (((ob >> 3) ^ (n_glob & 15)) << 3) | (ob & 7);
                uint2 v;
                v.x = f2bf2(acc[t][rg * 4 + 0], acc[t][rg * 4 + 1]);
                v.y = f2bf2(acc[t][rg * 4 + 2], acc[t][rg * 4 + 3]);
                *(uint2*)&T[((size_t)b * NPIX + n_glob) * HIDN + sc] = v;
            }
    } else {
        // gbuf[b][c][m=n_glob] SW16 key c&15 over 128-m sections
        const int sbase = n_glob & ~127;
        const int g16 = (n_glob >> 3) & 15, c7off = n_glob & 7;
#pragma unroll
        for (int t = 0; t < 2; ++t)
#pragma unroll
            for (int r = 0; r < 16; ++r) {
                const int c = oh * 64 + t * 32 + (r & 3) + 8 * (r >> 2) + 4 * lh;
                const int sc = sbase | ((g16 ^ (c & 15)) << 3) | c7off;
                gbuf[((size_t)b * HIDN + c) * NPIX + sc] = f2bf(acc[t][r]);
            }
    }
}

// ---------------------------------------------------------------- K2: colsum (+ zero O32)
// grid (mt=32, ng=8, b=4) = 1024. phi B-frags in registers; theta DMA chunks of 64 n.
__global__ __launch_bounds__(256, 3) void k_colsum(
    const unsigned short* __restrict__ thetaT,
    const unsigned short* __restrict__ phiT,
    float* __restrict__ colsum,
    float* __restrict__ O32)
{
    const int mt = blockIdx.x, ng = blockIdx.y, b = blockIdx.z;
    const int tid = threadIdx.x;
    {   // zero O32: 2048 floats per block
        const int blin = ((blockIdx.z * 8 + blockIdx.y) * 32 + blockIdx.x);
        float* p = O32 + (size_t)blin * 2048 + tid * 8;
        *(f32x4*)p = f32x4{0.f, 0.f, 0.f, 0.f};
        *(f32x4*)(p + 4) = f32x4{0.f, 0.f, 0.f, 0.f};
    }

    __shared__ alignas(16) unsigned short As[64][128];   // theta chunk

    const int wave = tid >> 6, lane = tid & 63;
    const int wn = wave & 1, wh = wave >> 1;
    const int l31 = lane & 31, lh = lane >> 5;
    const int key = l31 & 15;

    short8 bfrag[2][8];   // phi, m-half wn*64, 2 tiles x K=128
#pragma unroll
    for (int t = 0; t < 2; ++t) {
        const int m = mt * 128 + wn * 64 + t * 32 + l31;
        const unsigned short* src = phiT + ((size_t)b * NPIX + m) * HIDN;
#pragma unroll
        for (int ks = 0; ks < 8; ++ks)
            bfrag[t][ks] = *(const short8*)(src + (((ks * 2 + lh) ^ key) << 3));
    }

    float csum[2] = {0.f, 0.f};

    for (int nc = 0; nc < 8; ++nc) {
        const int n0 = ng * 512 + nc * 64;
        __syncthreads();
#pragma unroll
        for (int i = 0; i < 4; ++i) {
            const int u = i * 256 + tid;
            cp16(&As[0][0] + u * 8,
                 thetaT + ((size_t)b * NPIX + n0 + (u >> 4)) * HIDN + (u & 15) * 8);
        }
        __syncthreads();

        f32x16 acc[2];
#pragma unroll
        for (int r = 0; r < 16; ++r) { acc[0][r] = 0.f; acc[1][r] = 0.f; }
#pragma unroll
        for (int ks = 0; ks < 8; ++ks) {
            short8 a = *(const short8*)&As[wh * 32 + l31][(((ks * 2 + lh) ^ key) << 3)];
            acc[0] = __builtin_amdgcn_mfma_f32_32x32x16_bf16(a, bfrag[0][ks], acc[0], 0, 0, 0);
            acc[1] = __builtin_amdgcn_mfma_f32_32x32x16_bf16(a, bfrag[1][ks], acc[1], 0, 0, 0);
        }
#pragma unroll
        for (int t = 0; t < 2; ++t)
#pragma unroll
            for (int r = 0; r < 16; ++r) csum[t] += __expf(acc[t][r]);
    }

#pragma unroll
    for (int t = 0; t < 2; ++t) {
        float s = csum[t];
        s += __shfl_xor(s, 32);   // combine lh halves (row sets offset by 4)
        if (lh == 0)
            atomicAdd(&colsum[(size_t)b * NPIX + mt * 128 + wn * 64 + t * 32 + l31], s);
    }
}

// ---------------------------------------------------------------- K2b: g[c][m] *= 1/colsum[m]
__global__ __launch_bounds__(256) void k_scale_g(
    unsigned short* __restrict__ gbuf, const float* __restrict__ colsum)
{
    const int idx = blockIdx.x * 256 + threadIdx.x;   // 262144 granules
    const int row = idx >> 9;                          // b*128 + c
    const int sc = (idx & 511) * 8;                    // storage col (granule base)
    const int bb = row >> 7;
    // un-swizzle (SW16, key c&15): true m granule base
    const int mt = (sc & ~127) | ((((sc >> 3) & 15) ^ (row & 15)) << 3);
    uint4 v = *(uint4*)&gbuf[(size_t)row * NPIX + sc];
    float4 c0 = *(const float4*)&colsum[(size_t)bb * NPIX + mt];
    float4 c1 = *(const float4*)&colsum[(size_t)bb * NPIX + mt + 4];
    unsigned short* vs = (unsigned short*)&v;
    const float cs[8] = {c0.x, c0.y, c0.z, c0.w, c1.x, c1.y, c1.z, c1.w};
#pragma unroll
    for (int j = 0; j < 8; ++j) vs[j] = f2bf(bf2f(vs[j]) / cs[j]);
    *(uint4*)&gbuf[(size_t)row * NPIX + sc] = v;
}

// ---------------------------------------------------------------- K3: O += exp(S) @ g'^T
// grid (nt=64, ms=2, b=4) = 512 = 2/CU at 66.9 KB LDS. 128-m chunks, 16 per block.
// theta in LDS (once), phi A-frags in regs from global (pipelined), Gs DMA || S.
__global__ __launch_bounds__(256, 2) void k_attn(
    const unsigned short* __restrict__ thetaT,
    const unsigned short* __restrict__ phiT,
    const unsigned short* __restrict__ gbuf,   // pre-scaled by 1/colsum
    float* __restrict__ O32)                   // [B][N][HID] fp32, zeroed
{
    const int nt = blockIdx.x, ms = blockIdx.y, b = blockIdx.z;
    const int n0 = nt * 64;

    __shared__ alignas(16) unsigned short Ts[64][128];   // theta [n][k] SW16 (16K)
    __shared__ alignas(16) unsigned short Gs[128][128];  // g' [c][m] SW16 (32K)
    __shared__ alignas(16) unsigned short Ps[64][136];   // P [n][m] XOR16 + pad (17.4K)

    const int tid = threadIdx.x;
    const int wave = tid >> 6, lane = tid & 63;
    const int q = wave;                        // S: m-quarter
    const int nh = wave >> 1, ch = wave & 1;   // PV: n-half, c-half
    const int l31 = lane & 31, lh = lane >> 5;
    const int key = l31 & 15;

#pragma unroll
    for (int i = 0; i < 4; ++i) {   // stage theta ONCE: 64 rows x 128
        const int u = i * 256 + tid;
        cp16(&Ts[0][0] + u * 8,
             thetaT + ((size_t)b * NPIX + n0 + (u >> 4)) * HIDN + (u & 15) * 8);
    }

    // phi A-frags for chunk 0 (rows m = ms*2048 + q*32 + l31, K=128)
    short8 pcur[8], pnxt[8];
    {
        const unsigned short* src = phiT + ((size_t)b * NPIX + ms * 2048 + q * 32 + l31) * HIDN;
#pragma unroll
        for (int ks = 0; ks < 8; ++ks)
            pcur[ks] = *(const short8*)(src + (((ks * 2 + lh) ^ key) << 3));
    }

    f32x16 accO[2];
#pragma unroll
    for (int r = 0; r < 16; ++r) { accO[0][r] = 0.f; accO[1][r] = 0.f; }

    __syncthreads();   // Ts staged (drains DMA + phi loads)

    for (int mc = 0; mc < 16; ++mc) {
        const int m0 = ms * 2048 + mc * 128;
        // Gs DMA for this chunk — overlaps the whole S phase (drained at barrier A)
#pragma unroll
        for (int i = 0; i < 8; ++i) {
            const int u = i * 256 + tid;
            cp16(&Gs[0][0] + u * 8,
                 gbuf + ((size_t)b * HIDN + (u >> 4)) * NPIX + m0 + (u & 15) * 8);
        }
        if (mc < 15) {   // prefetch next chunk's phi frags
            const unsigned short* src =
                phiT + ((size_t)b * NPIX + m0 + 128 + q * 32 + l31) * HIDN;
#pragma unroll
            for (int ks = 0; ks < 8; ++ks)
                pnxt[ks] = *(const short8*)(src + (((ks * 2 + lh) ^ key) << 3));
        }

        // ---- S: wave = m-quarter q x n-full 64 (2 theta tiles). D col=n, rows=m.
        f32x16 accS[2];
#pragma unroll
        for (int r = 0; r < 16; ++r) { accS[0][r] = 0.f; accS[1][r] = 0.f; }
#pragma unroll
        for (int ks = 0; ks < 8; ++ks) {
            const int g = ((ks * 2 + lh) ^ key) << 3;
            short8 t0 = *(const short8*)&Ts[l31][g];
            short8 t1 = *(const short8*)&Ts[32 + l31][g];
            accS[0] = __builtin_amdgcn_mfma_f32_32x32x16_bf16(pcur[ks], t0, accS[0], 0, 0, 0);
            accS[1] = __builtin_amdgcn_mfma_f32_32x32x16_bf16(pcur[ks], t1, accS[1], 0, 0, 0);
        }
        // ---- P = exp(S) -> Ps packed b64 writes (lane: col n fixed, 4-consec m)
#pragma unroll
        for (int t = 0; t < 2; ++t) {
            const int n = t * 32 + l31;
#pragma unroll
            for (int rg = 0; rg < 4; ++rg) {
                uint2 v;
                v.x = f2bf2(__expf(accS[t][rg * 4 + 0]), __expf(accS[t][rg * 4 + 1]));
                v.y = f2bf2(__expf(accS[t][rg * 4 + 2]), __expf(accS[t][rg * 4 + 3]));
                const int gm = q * 4 + rg;                  // m-granule (uniform/instr)
                const int col = (((gm ^ (n & 15)) << 3) | (4 * lh));
                *(uint2*)&Ps[n][col] = v;
            }
        }
        __syncthreads();   // A: Ps visible, Gs DMA drained

        // ---- PV: wave = n-half x c-half64. O[n][c] += P @ g'^T, K=128.
#pragma unroll
        for (int ks = 0; ks < 8; ++ks) {
            const int g = ((ks * 2 + lh) ^ key) << 3;
            short8 pa = *(const short8*)&Ps[nh * 32 + l31][g];
            short8 g0 = *(const short8*)&Gs[ch * 64 + l31][g];
            short8 g1 = *(const short8*)&Gs[ch * 64 + 32 + l31][g];
            accO[0] = __builtin_amdgcn_mfma_f32_32x32x16_bf16(pa, g0, accO[0], 0, 0, 0);
            accO[1] = __builtin_amdgcn_mfma_f32_32x32x16_bf16(pa, g1, accO[1], 0, 0, 0);
        }
        __syncthreads();   // B: PV done -> next chunk may overwrite Gs/Ps

#pragma unroll
        for (int ks = 0; ks < 8; ++ks) pcur[ks] = pnxt[ks];
    }

#pragma unroll
    for (int t = 0; t < 2; ++t)
#pragma unroll
        for (int r = 0; r < 16; ++r) {
            const int n = n0 + nh * 32 + (r & 3) + 8 * (r >> 2) + 4 * lh;
            const int c = ch * 64 + t * 32 + l31;
            atomicAdd(&O32[((size_t)b * NPIX + n) * HIDN + c], accO[t][r]);
        }
}

// ---------------------------------------------------------------- K4: mask GEMM + residual
// grid (nt=64, ct=2, b=4) = 512. Block tile [128 co][64 n], single K=128 pass.
__global__ __launch_bounds__(256, 3) void k_mask(
    const unsigned short* __restrict__ Wm,   // [256][128] bf16 SW16 key o&15
    const float* __restrict__ O32,           // [B][N][HID] fp32 plain
    const float* __restrict__ x,
    float* __restrict__ out)
{
    const int nt = blockIdx.x, ct = blockIdx.y, b = blockIdx.z;
    __shared__ alignas(16) unsigned short As[128][128];  // w_mask rows SW16
    __shared__ alignas(16) unsigned short Bs[64][128];   // O bf16, SW8 key n&7

    const int tid = threadIdx.x;
    const int wave = tid >> 6, lane = tid & 63;
    const int oh = wave >> 1, nh = wave & 1;
    const int l31 = lane & 31, lh = lane >> 5;
    const int key = l31 & 15;

#pragma unroll
    for (int i = 0; i < 8; ++i) {   // As DMA: 128 rows x 128
        const int u = i * 256 + tid;
        cp16(&As[0][0] + u * 8, Wm + (ct * 128 + (u >> 4)) * HIDN + (u & 15) * 8);
    }
    {   // Bs: convert O32 [64 n][128 h] -> bf16 SW8(n&7)
        const int n_loc = tid >> 2, seg = (tid & 3) * 32;
        const float* src = O32 + ((size_t)b * NPIX + nt * 64 + n_loc) * HIDN + seg;
        const int k7 = n_loc & 7;
#pragma unroll
        for (int j = 0; j < 4; ++j) {          // 4 granules of 8
            const int gr = (seg >> 3) + j;
            const int sg = (gr & ~7) | ((gr & 7) ^ k7);
            const float* s8 = src + j * 8;
            unsigned* d = (unsigned*)&Bs[n_loc][sg * 8];
#pragma unroll
            for (int k = 0; k < 4; ++k) d[k] = f2bf2(s8[2 * k], s8[2 * k + 1]);
        }
    }
    __syncthreads();

    f32x16 acc[2];
#pragma unroll
    for (int r = 0; r < 16; ++r) { acc[0][r] = 0.f; acc[1][r] = 0.f; }
#pragma unroll
    for (int ks = 0; ks < 8; ++ks) {
        const int gr = ks * 2 + lh;
        const int sgb = ((gr & ~7) | ((gr & 7) ^ (l31 & 7))) << 3;
        short8 bb = *(const short8*)&Bs[nh * 32 + l31][sgb];
#pragma unroll
        for (int t = 0; t < 2; ++t) {
            short8 a = *(const short8*)&As[oh * 64 + t * 32 + l31][((gr ^ key) << 3)];
            acc[t] = __builtin_amdgcn_mfma_f32_32x32x16_bf16(a, bb, acc[t], 0, 0, 0);
        }
    }

    const int n = nt * 64 + nh * 32 + l31;
#pragma unroll
    for (int t = 0; t < 2; ++t)
#pragma unroll
        for (int r = 0; r < 16; ++r) {
            const int co = ct * 128 + oh * 64 + t * 32 + (r & 3) + 8 * (r >> 2) + 4 * lh;
            const size_t idx = ((size_t)b * CIN + co) * NPIX + n;
            out[idx] = acc[t][r] + x[idx];
        }
}

// ---------------------------------------------------------------- launch
extern "C" void kernel_launch(void* const* d_in, const int* in_sizes, int n_in,
                              void* d_out, int out_size, void* d_ws, size_t ws_size,
                              hipStream_t stream)
{
    (void)in_sizes; (void)n_in; (void)out_size; (void)ws_size;
    const float* x       = (const float*)d_in[0];
    const float* w_phi   = (const float*)d_in[1];
    const float* w_theta = (const float*)d_in[2];
    const float* w_g     = (const float*)d_in[3];
    const float* w_mask  = (const float*)d_in[4];
    float* out = (float*)d_out;

    char* ws = (char*)d_ws;
    unsigned short* phiT   = (unsigned short*)(ws);              //  4 MB
    unsigned short* thetaT = (unsigned short*)(ws + 4194304);    //  4 MB
    unsigned short* gbuf   = (unsigned short*)(ws + 8388608);    //  4 MB
    float*          colsum = (float*)(ws + 12582912);            // 64 KB
    // xT (bf16, prep->proj) and O32 (fp32, colsum->mask) alias: xT dead after k_proj,
    // O32 zeroed inside k_colsum which runs after k_proj.
    unsigned short* xT     = (unsigned short*)(ws + 12648448);   //  8 MB
    float*          O32    = (float*)(ws + 12648448);
    unsigned short* Wp     = (unsigned short*)(ws + 21037056);   // 64 KB
    unsigned short* Wt     = (unsigned short*)(ws + 21102592);   // 64 KB
    unsigned short* Wg     = (unsigned short*)(ws + 21168128);   // 64 KB
    unsigned short* Wm     = (unsigned short*)(ws + 21233664);   // 64 KB
    // total ws use: 21,299,200 bytes

    k_prep_w <<<dim3(32),        256, 0, stream>>>(w_phi, w_theta, w_g, w_mask, Wp, Wt, Wg, Wm);
    k_prep_x <<<dim3(64, 4, 4),  256, 0, stream>>>(x, xT, colsum);
    k_proj   <<<dim3(64, 3, 4),  256, 0, stream>>>(Wp, Wt, Wg, xT, phiT, thetaT, gbuf);
    k_colsum <<<dim3(32, 8, 4),  256, 0, stream>>>(thetaT, phiT, colsum, O32);
    k_scale_g<<<dim3(1024),      256, 0, stream>>>(gbuf, colsum);
    k_attn   <<<dim3(64, 2, 4),  256, 0, stream>>>(thetaT, phiT, gbuf, O32);
    k_mask   <<<dim3(64, 2, 4),  256, 0, stream>>>(Wm, O32, x, out);
}

// Round 6
// 169.512 us; speedup vs baseline: 1.1439x; 1.1439x over previous
//
#include <hip/hip_runtime.h>

// NonLocalBlock: B=4, C=256, HID=128, N=64*64=4096, all-f32 in/out.
// Pipeline (bf16 MFMA 32x32x16, fp32 accum):
//   P1 k_prep_w : w_phi/theta/g/mask -> bf16, granule-swizzled (key o&15)
//   P2 k_prep_x : x -> xT[b][n][256] bf16 swizzled (key n&15); zero colsum
//   K1 k_proj   : phiT/thetaT[b][n][128] (SW16 key n&15), gbuf[b][c][m] (SW16 key c&15)
//   K2 k_colsum : colsum[b][m] = sum_n exp(S[n][m]); also zeroes O32
//                 (theta DMA double-buffered, 1 barrier/chunk, phi B-frags in regs)
//   K2b k_scale_g: g[c][m] *= 1/colsum[m]
//   K3 k_attn   : O32[b][n][c] += sum_m exp(S[n][m]) * g'[c][m]
//                 theta+phi in REGISTERS (S phase touches no LDS), Gs double-
//                 buffered DMA overlapping PV, Ps stride-128 XOR16 (conflict-free),
//                 packed b64 Ps writes via operand-swapped S, ms-split x2 + atomics.
//   K4 k_mask   : out = w_mask @ O^T + x  (DMA A-stage, single K pass)
// Swizzle SW16 (128-col sections): sc = (c&~127)|((((c>>3)&15)^(key&15))<<3)|(c&7)
// ws: phiT(4M) thetaT(4M) gbuf(4M) colsum(64K) XO=xT|O32(8M, aliased) W(256K)

#define NB   4
#define CIN  256
#define HIDN 128
#define NPIX 4096

typedef __attribute__((ext_vector_type(8))) short short8;
typedef __attribute__((ext_vector_type(4))) float f32x4;
typedef __attribute__((ext_vector_type(16))) float f32x16;

__device__ __forceinline__ unsigned short f2bf(float f) {
    unsigned u = __builtin_bit_cast(unsigned, f);
    u += 0x7fffu + ((u >> 16) & 1u);          // RNE; inputs finite
    return (unsigned short)(u >> 16);
}
__device__ __forceinline__ unsigned f2bf2(float lo, float hi) {
    return (unsigned)f2bf(lo) | ((unsigned)f2bf(hi) << 16);
}
__device__ __forceinline__ float bf2f(unsigned short s) {
    return __builtin_bit_cast(float, (unsigned)s << 16);
}
// async global->LDS, 16B/lane; LDS dest = wave-uniform base + lane*16
__device__ __forceinline__ void cp16(void* lds, const void* g) {
    __builtin_amdgcn_global_load_lds(
        (const __attribute__((address_space(1))) unsigned int*)g,
        (__attribute__((address_space(3))) unsigned int*)lds, 16, 0, 0);
}

// ---------------------------------------------------------------- P1: W conversion
// 32 blocks: [0,8) w_phi, [8,16) w_theta, [16,24) w_g, [24,32) w_mask.
__global__ __launch_bounds__(256) void k_prep_w(
    const float* __restrict__ wp, const float* __restrict__ wt,
    const float* __restrict__ wg, const float* __restrict__ wm,
    unsigned short* __restrict__ Wp, unsigned short* __restrict__ Wt,
    unsigned short* __restrict__ Wg, unsigned short* __restrict__ Wm)
{
    const int which = blockIdx.x >> 3;
    const float* src = (which == 0) ? wp : (which == 1) ? wt : (which == 2) ? wg : wm;
    unsigned short* dst = (which == 0) ? Wp : (which == 1) ? Wt : (which == 2) ? Wg : Wm;
#pragma unroll
    for (int t = 0; t < 2; ++t) {
        const int gidx = ((blockIdx.x & 7) * 256 + threadIdx.x) * 2 + t;  // 4096 granules
        int o, srcc, dstc;
        if (which < 3) {                       // [128][256]
            o = gidx >> 5;
            const int gc = gidx & 31;
            const int sg = (gc & ~15) | ((gc & 15) ^ (o & 15));
            srcc = o * 256 + gc * 8; dstc = o * 256 + sg * 8;
        } else {                               // [256][128]
            o = gidx >> 4;
            const int gc = gidx & 15;
            const int sg = gc ^ (o & 15);
            srcc = o * 128 + gc * 8; dstc = o * 128 + sg * 8;
        }
        float4 a = *(const float4*)&src[srcc];
        float4 b = *(const float4*)&src[srcc + 4];
        uint4 v;
        v.x = f2bf2(a.x, a.y); v.y = f2bf2(a.z, a.w);
        v.z = f2bf2(b.x, b.y); v.w = f2bf2(b.z, b.w);
        *(uint4*)&dst[dstc] = v;
    }
}

// ---------------------------------------------------------------- P2: x -> xT bf16 swizzled
// grid (nt=64, ct=4, b=4). Tile [64 c][64 n]. Also zeroes colsum (ct==0 blocks).
__global__ __launch_bounds__(256) void k_prep_x(
    const float* __restrict__ x,
    unsigned short* __restrict__ xT,   // [B][N][256] SW16 key n&15
    float* __restrict__ colsum)
{
    const int nt = blockIdx.x, ct = blockIdx.y, b = blockIdx.z;
    const int tid = threadIdx.x;
    if (ct == 0 && tid < 64) colsum[(size_t)b * NPIX + nt * 64 + tid] = 0.f;

    __shared__ unsigned short Ls[64][66];
    {   // read x tile [64 c][64 n] coalesced, convert, store LDS
        const int c_loc = tid >> 2, n_seg = (tid & 3) * 16;
        const float* src = x + ((size_t)(b * CIN + ct * 64 + c_loc)) * NPIX + nt * 64 + n_seg;
#pragma unroll
        for (int j = 0; j < 8; ++j)
            *(unsigned*)&Ls[c_loc][n_seg + 2 * j] = f2bf2(src[2 * j], src[2 * j + 1]);
    }
    __syncthreads();
    {   // write xT rows: thread handles row n_loc, 16 c values (2 granules)
        const int n_loc = tid >> 2, c_seg = (tid & 3) * 16;
        const int n_glob = nt * 64 + n_loc;
        unsigned short tmp[16];
#pragma unroll
        for (int j = 0; j < 16; ++j) tmp[j] = Ls[c_seg + j][n_loc];
#pragma unroll
        for (int gr = 0; gr < 2; ++gr) {
            const int c_base = ct * 64 + c_seg + gr * 8;
            const int sec = c_base >> 7;
            const int sg = (((c_base >> 3) & 15) ^ (n_glob & 15));
            *(uint4*)&xT[((size_t)b * NPIX + n_glob) * CIN + sec * 128 + sg * 8] =
                *(uint4*)&tmp[gr * 8];
        }
    }
}

// ---------------------------------------------------------------- K1: projections (GEMM)
// grid (nt=64, ot=3, b=4) = 768 = 3/CU. Block tile [128 o][64 n], K=256 in 2 halves.
__global__ __launch_bounds__(256, 3) void k_proj(
    const unsigned short* __restrict__ Wp,   // [128][256] bf16 SW16 key o&15
    const unsigned short* __restrict__ Wt,
    const unsigned short* __restrict__ Wg,
    const unsigned short* __restrict__ xT,   // [B][N][256] SW16 key n&15
    unsigned short* __restrict__ phiT,       // [B][N][128] SW16 key n&15
    unsigned short* __restrict__ thetaT,
    unsigned short* __restrict__ gbuf)       // [B][128][N] SW16 key c&15
{
    const int nt = blockIdx.x, ot = blockIdx.y, b = blockIdx.z;
    const unsigned short* W = (ot == 0) ? Wp : (ot == 1) ? Wt : Wg;

    __shared__ alignas(16) unsigned short Aw[128][128];  // W k-half
    __shared__ alignas(16) unsigned short Bx[64][128];   // xT k-half

    const int tid = threadIdx.x;
    const int wave = tid >> 6, lane = tid & 63;
    const int oh = wave >> 1, nh = wave & 1;
    const int l31 = lane & 31, lh = lane >> 5;
    const int key = l31 & 15;

    f32x16 acc[2];
#pragma unroll
    for (int r = 0; r < 16; ++r) { acc[0][r] = 0.f; acc[1][r] = 0.f; }

    for (int kh = 0; kh < 2; ++kh) {
        __syncthreads();
#pragma unroll
        for (int i = 0; i < 8; ++i) {   // Aw: 128 rows x 128 shorts
            const int u = i * 256 + tid;
            cp16(&Aw[0][0] + u * 8, W + (u >> 4) * 256 + kh * 128 + (u & 15) * 8);
        }
#pragma unroll
        for (int i = 0; i < 4; ++i) {   // Bx: 64 rows x 128 shorts
            const int u = i * 256 + tid;
            cp16(&Bx[0][0] + u * 8,
                 xT + ((size_t)b * NPIX + nt * 64 + (u >> 4)) * CIN + kh * 128 + (u & 15) * 8);
        }
        __syncthreads();
#pragma unroll
        for (int ks = 0; ks < 8; ++ks) {
            const int g = ((ks * 2 + lh) ^ key) << 3;
            short8 bb = *(const short8*)&Bx[nh * 32 + l31][g];
#pragma unroll
            for (int t = 0; t < 2; ++t) {
                short8 a = *(const short8*)&Aw[oh * 64 + t * 32 + l31][g];
                acc[t] = __builtin_amdgcn_mfma_f32_32x32x16_bf16(a, bb, acc[t], 0, 0, 0);
            }
        }
    }

    const int n_glob = nt * 64 + nh * 32 + l31;
    if (ot < 2) {
        unsigned short* T = (ot == 0) ? phiT : thetaT;
#pragma unroll
        for (int t = 0; t < 2; ++t)
#pragma unroll
            for (int rg = 0; rg < 4; ++rg) {
                const int ob = oh * 64 + t * 32 + 8 * rg + 4 * lh;   // 4 consecutive o
                const int sc = (((ob >> 3) ^ (n_glob & 15)) << 3) | (ob & 7);
                uint2 v;
                v.x = f2bf2(acc[t][rg * 4 + 0], acc[t][rg * 4 + 1]);
                v.y = f2bf2(acc[t][rg * 4 + 2], acc[t][rg * 4 + 3]);
                *(uint2*)&T[((size_t)b * NPIX + n_glob) * HIDN + sc] = v;
            }
    } else {
        // gbuf[b][c][m=n_glob] SW16 key c&15 over 128-m sections
        const int sbase = n_glob & ~127;
        const int g16 = (n_glob >> 3) & 15, c7off = n_glob & 7;
#pragma unroll
        for (int t = 0; t < 2; ++t)
#pragma unroll
            for (int r = 0; r < 16; ++r) {
                const int c = oh * 64 + t * 32 + (r & 3) + 8 * (r >> 2) + 4 * lh;
                const int sc = sbase | ((g16 ^ (c & 15)) << 3) | c7off;
                gbuf[((size_t)b * HIDN + c) * NPIX + sc] = f2bf(acc[t][r]);
            }
    }
}

// ---------------------------------------------------------------- K2: colsum (+ zero O32)
// grid (mt=32, ng=8, b=4) = 1024. phi B-frags in registers; theta DMA double-buffered.
__global__ __launch_bounds__(256, 3) void k_colsum(
    const unsigned short* __restrict__ thetaT,
    const unsigned short* __restrict__ phiT,
    float* __restrict__ colsum,
    float* __restrict__ O32)
{
    const int mt = blockIdx.x, ng = blockIdx.y, b = blockIdx.z;
    const int tid = threadIdx.x;
    {   // zero O32: 2048 floats per block
        const int blin = ((blockIdx.z * 8 + blockIdx.y) * 32 + blockIdx.x);
        float* p = O32 + (size_t)blin * 2048 + tid * 8;
        *(f32x4*)p = f32x4{0.f, 0.f, 0.f, 0.f};
        *(f32x4*)(p + 4) = f32x4{0.f, 0.f, 0.f, 0.f};
    }

    __shared__ alignas(16) unsigned short As[2][64][128];   // theta chunks, dbuf (32K)

    const int wave = tid >> 6, lane = tid & 63;
    const int wn = wave & 1, wh = wave >> 1;
    const int l31 = lane & 31, lh = lane >> 5;
    const int key = l31 & 15;

    short8 bfrag[2][8];   // phi, m-half wn*64, 2 tiles x K=128
#pragma unroll
    for (int t = 0; t < 2; ++t) {
        const int m = mt * 128 + wn * 64 + t * 32 + l31;
        const unsigned short* src = phiT + ((size_t)b * NPIX + m) * HIDN;
#pragma unroll
        for (int ks = 0; ks < 8; ++ks)
            bfrag[t][ks] = *(const short8*)(src + (((ks * 2 + lh) ^ key) << 3));
    }

#pragma unroll
    for (int i = 0; i < 4; ++i) {   // chunk 0 DMA -> buf 0
        const int u = i * 256 + tid;
        cp16(&As[0][0][0] + u * 8,
             thetaT + ((size_t)b * NPIX + ng * 512 + (u >> 4)) * HIDN + (u & 15) * 8);
    }

    float csum[2] = {0.f, 0.f};

    for (int nc = 0; nc < 8; ++nc) {
        const int cur = nc & 1;
        __syncthreads();   // As[cur] DMA drained; prev chunk's reads complete
        if (nc < 7) {      // issue next chunk -> other buf; overlaps this chunk's math
            const int n1 = ng * 512 + (nc + 1) * 64;
#pragma unroll
            for (int i = 0; i < 4; ++i) {
                const int u = i * 256 + tid;
                cp16(&As[cur ^ 1][0][0] + u * 8,
                     thetaT + ((size_t)b * NPIX + n1 + (u >> 4)) * HIDN + (u & 15) * 8);
            }
        }

        f32x16 acc[2];
#pragma unroll
        for (int r = 0; r < 16; ++r) { acc[0][r] = 0.f; acc[1][r] = 0.f; }
#pragma unroll
        for (int ks = 0; ks < 8; ++ks) {
            short8 a = *(const short8*)&As[cur][wh * 32 + l31][(((ks * 2 + lh) ^ key) << 3)];
            acc[0] = __builtin_amdgcn_mfma_f32_32x32x16_bf16(a, bfrag[0][ks], acc[0], 0, 0, 0);
            acc[1] = __builtin_amdgcn_mfma_f32_32x32x16_bf16(a, bfrag[1][ks], acc[1], 0, 0, 0);
        }
#pragma unroll
        for (int t = 0; t < 2; ++t)
#pragma unroll
            for (int r = 0; r < 16; ++r) csum[t] += __expf(acc[t][r]);
    }

#pragma unroll
    for (int t = 0; t < 2; ++t) {
        float s = csum[t];
        s += __shfl_xor(s, 32);   // combine lh halves (row sets offset by 4)
        if (lh == 0)
            atomicAdd(&colsum[(size_t)b * NPIX + mt * 128 + wn * 64 + t * 32 + l31], s);
    }
}

// ---------------------------------------------------------------- K2b: g[c][m] *= 1/colsum[m]
__global__ __launch_bounds__(256) void k_scale_g(
    unsigned short* __restrict__ gbuf, const float* __restrict__ colsum)
{
    const int idx = blockIdx.x * 256 + threadIdx.x;   // 262144 granules
    const int row = idx >> 9;                          // b*128 + c
    const int sc = (idx & 511) * 8;                    // storage col (granule base)
    const int bb = row >> 7;
    // un-swizzle (SW16, key c&15): true m granule base
    const int mt = (sc & ~127) | ((((sc >> 3) & 15) ^ (row & 15)) << 3);
    uint4 v = *(uint4*)&gbuf[(size_t)row * NPIX + sc];
    float4 c0 = *(const float4*)&colsum[(size_t)bb * NPIX + mt];
    float4 c1 = *(const float4*)&colsum[(size_t)bb * NPIX + mt + 4];
    unsigned short* vs = (unsigned short*)&v;
    const float cs[8] = {c0.x, c0.y, c0.z, c0.w, c1.x, c1.y, c1.z, c1.w};
#pragma unroll
    for (int j = 0; j < 8; ++j) vs[j] = f2bf(bf2f(vs[j]) / cs[j]);
    *(uint4*)&gbuf[(size_t)row * NPIX + sc] = v;
}

// ---------------------------------------------------------------- K3: O += exp(S) @ g'^T
// grid (nt=64, ms=2, b=4) = 512 = 2/CU at 80 KB LDS. 128-m chunks, 16 per block.
// theta+phi in registers (S uses no LDS); Gs double-buffered DMA overlaps PV;
// Ps stride-128 + XOR16 (zero-conflict pattern), packed b64 writes.
__global__ __launch_bounds__(256, 2) void k_attn(
    const unsigned short* __restrict__ thetaT,
    const unsigned short* __restrict__ phiT,
    const unsigned short* __restrict__ gbuf,   // pre-scaled by 1/colsum
    float* __restrict__ O32)                   // [B][N][HID] fp32, zeroed
{
    const int nt = blockIdx.x, ms = blockIdx.y, b = blockIdx.z;
    const int n0 = nt * 64;

    __shared__ alignas(16) unsigned short Gs[2][128][128];  // g' [c][m] SW16 dbuf (64K)
    __shared__ alignas(16) unsigned short Ps[64][128];      // P [n][m] XOR16 (16K)

    const int tid = threadIdx.x;
    const int wave = tid >> 6, lane = tid & 63;
    const int q = wave;                        // S: m-quarter
    const int nh = wave >> 1, ch = wave & 1;   // PV: n-half, c-half
    const int l31 = lane & 31, lh = lane >> 5;
    const int key = l31 & 15;

    // theta B-frags register-resident: 2 n-tiles x K=128
    short8 tfrag[2][8];
#pragma unroll
    for (int t = 0; t < 2; ++t) {
        const unsigned short* src =
            thetaT + ((size_t)b * NPIX + n0 + t * 32 + l31) * HIDN;
#pragma unroll
        for (int ks = 0; ks < 8; ++ks)
            tfrag[t][ks] = *(const short8*)(src + (((ks * 2 + lh) ^ key) << 3));
    }
    // phi A-frags for chunk 0 (rows m = ms*2048 + q*32 + l31, K=128)
    short8 pcur[8], pnxt[8];
    {
        const unsigned short* src =
            phiT + ((size_t)b * NPIX + ms * 2048 + q * 32 + l31) * HIDN;
#pragma unroll
        for (int ks = 0; ks < 8; ++ks)
            pcur[ks] = *(const short8*)(src + (((ks * 2 + lh) ^ key) << 3));
    }
    // Gs chunk 0 DMA -> buf 0 (overlaps S of chunk 0, drained at barrier A)
#pragma unroll
    for (int i = 0; i < 8; ++i) {
        const int u = i * 256 + tid;
        cp16(&Gs[0][0][0] + u * 8,
             gbuf + ((size_t)b * HIDN + (u >> 4)) * NPIX + ms * 2048 + (u & 15) * 8);
    }

    f32x16 accO[2];
#pragma unroll
    for (int r = 0; r < 16; ++r) { accO[0][r] = 0.f; accO[1][r] = 0.f; }

    for (int mc = 0; mc < 16; ++mc) {
        const int cur = mc & 1;
        const int m0 = ms * 2048 + mc * 128;

        // ---- S: wave = m-quarter q x n-full 64; regs only. D col=n, rows=m.
        f32x16 accS[2];
#pragma unroll
        for (int r = 0; r < 16; ++r) { accS[0][r] = 0.f; accS[1][r] = 0.f; }
#pragma unroll
        for (int ks = 0; ks < 8; ++ks) {
            accS[0] = __builtin_amdgcn_mfma_f32_32x32x16_bf16(pcur[ks], tfrag[0][ks], accS[0], 0, 0, 0);
            accS[1] = __builtin_amdgcn_mfma_f32_32x32x16_bf16(pcur[ks], tfrag[1][ks], accS[1], 0, 0, 0);
        }
        if (mc < 15) {   // prefetch next chunk's phi frags
            const unsigned short* src =
                phiT + ((size_t)b * NPIX + m0 + 128 + q * 32 + l31) * HIDN;
#pragma unroll
            for (int ks = 0; ks < 8; ++ks)
                pnxt[ks] = *(const short8*)(src + (((ks * 2 + lh) ^ key) << 3));
        }
        // ---- P = exp(S) -> Ps packed b64 (row m-granule gm, col n; stride 128)
#pragma unroll
        for (int t = 0; t < 2; ++t) {
            const int n = t * 32 + l31;
#pragma unroll
            for (int rg = 0; rg < 4; ++rg) {
                uint2 v;
                v.x = f2bf2(__expf(accS[t][rg * 4 + 0]), __expf(accS[t][rg * 4 + 1]));
                v.y = f2bf2(__expf(accS[t][rg * 4 + 2]), __expf(accS[t][rg * 4 + 3]));
                const int gm = q * 4 + rg;                  // m-granule (uniform/instr)
                const int col = ((gm ^ (n & 15)) << 3) | (4 * lh);
                *(uint2*)&Ps[n][col] = v;
            }
        }
        __syncthreads();   // A: Ps visible; Gs[cur] DMA drained
        if (mc < 15) {     // issue next Gs DMA -> other buf (overlaps PV below)
#pragma unroll
            for (int i = 0; i < 8; ++i) {
                const int u = i * 256 + tid;
                cp16(&Gs[cur ^ 1][0][0] + u * 8,
                     gbuf + ((size_t)b * HIDN + (u >> 4)) * NPIX + m0 + 128 + (u & 15) * 8);
            }
        }
        // ---- PV: wave = n-half x c-half64. O[n][c] += P @ g'^T, K=128.
#pragma unroll
        for (int ks = 0; ks < 8; ++ks) {
            const int g = ((ks * 2 + lh) ^ key) << 3;
            short8 pa = *(const short8*)&Ps[nh * 32 + l31][g];
            short8 g0 = *(const short8*)&Gs[cur][ch * 64 + l31][g];
            short8 g1 = *(const short8*)&Gs[cur][ch * 64 + 32 + l31][g];
            accO[0] = __builtin_amdgcn_mfma_f32_32x32x16_bf16(pa, g0, accO[0], 0, 0, 0);
            accO[1] = __builtin_amdgcn_mfma_f32_32x32x16_bf16(pa, g1, accO[1], 0, 0, 0);
        }
        __syncthreads();   // B: PV done -> Ps reusable; Gs[cur] reusable at mc+2

#pragma unroll
        for (int ks = 0; ks < 8; ++ks) pcur[ks] = pnxt[ks];
    }

#pragma unroll
    for (int t = 0; t < 2; ++t)
#pragma unroll
        for (int r = 0; r < 16; ++r) {
            const int n = n0 + nh * 32 + (r & 3) + 8 * (r >> 2) + 4 * lh;
            const int c = ch * 64 + t * 32 + l31;
            atomicAdd(&O32[((size_t)b * NPIX + n) * HIDN + c], accO[t][r]);
        }
}

// ---------------------------------------------------------------- K4: mask GEMM + residual
// grid (nt=64, ct=2, b=4) = 512. Block tile [128 co][64 n], single K=128 pass.
__global__ __launch_bounds__(256, 3) void k_mask(
    const unsigned short* __restrict__ Wm,   // [256][128] bf16 SW16 key o&15
    const float* __restrict__ O32,           // [B][N][HID] fp32 plain
    const float* __restrict__ x,
    float* __restrict__ out)
{
    const int nt = blockIdx.x, ct = blockIdx.y, b = blockIdx.z;
    __shared__ alignas(16) unsigned short As[128][128];  // w_mask rows SW16
    __shared__ alignas(16) unsigned short Bs[64][128];   // O bf16, SW8 key n&7

    const int tid = threadIdx.x;
    const int wave = tid >> 6, lane = tid & 63;
    const int oh = wave >> 1, nh = wave & 1;
    const int l31 = lane & 31, lh = lane >> 5;
    const int key = l31 & 15;

#pragma unroll
    for (int i = 0; i < 8; ++i) {   // As DMA: 128 rows x 128
        const int u = i * 256 + tid;
        cp16(&As[0][0] + u * 8, Wm + (ct * 128 + (u >> 4)) * HIDN + (u & 15) * 8);
    }
    {   // Bs: convert O32 [64 n][128 h] -> bf16 SW8(n&7)
        const int n_loc = tid >> 2, seg = (tid & 3) * 32;
        const float* src = O32 + ((size_t)b * NPIX + nt * 64 + n_loc) * HIDN + seg;
        const int k7 = n_loc & 7;
#pragma unroll
        for (int j = 0; j < 4; ++j) {          // 4 granules of 8
            const int gr = (seg >> 3) + j;
            const int sg = (gr & ~7) | ((gr & 7) ^ k7);
            const float* s8 = src + j * 8;
            unsigned* d = (unsigned*)&Bs[n_loc][sg * 8];
#pragma unroll
            for (int k = 0; k < 4; ++k) d[k] = f2bf2(s8[2 * k], s8[2 * k + 1]);
        }
    }
    __syncthreads();

    f32x16 acc[2];
#pragma unroll
    for (int r = 0; r < 16; ++r) { acc[0][r] = 0.f; acc[1][r] = 0.f; }
#pragma unroll
    for (int ks = 0; ks < 8; ++ks) {
        const int gr = ks * 2 + lh;
        const int sgb = ((gr & ~7) | ((gr & 7) ^ (l31 & 7))) << 3;
        short8 bb = *(const short8*)&Bs[nh * 32 + l31][sgb];
#pragma unroll
        for (int t = 0; t < 2; ++t) {
            short8 a = *(const short8*)&As[oh * 64 + t * 32 + l31][((gr ^ key) << 3)];
            acc[t] = __builtin_amdgcn_mfma_f32_32x32x16_bf16(a, bb, acc[t], 0, 0, 0);
        }
    }

    const int n = nt * 64 + nh * 32 + l31;
#pragma unroll
    for (int t = 0; t < 2; ++t)
#pragma unroll
        for (int r = 0; r < 16; ++r) {
            const int co = ct * 128 + oh * 64 + t * 32 + (r & 3) + 8 * (r >> 2) + 4 * lh;
            const size_t idx = ((size_t)b * CIN + co) * NPIX + n;
            out[idx] = acc[t][r] + x[idx];
        }
}

// ---------------------------------------------------------------- launch
extern "C" void kernel_launch(void* const* d_in, const int* in_sizes, int n_in,
                              void* d_out, int out_size, void* d_ws, size_t ws_size,
                              hipStream_t stream)
{
    (void)in_sizes; (void)n_in; (void)out_size; (void)ws_size;
    const float* x       = (const float*)d_in[0];
    const float* w_phi   = (const float*)d_in[1];
    const float* w_theta = (const float*)d_in[2];
    const float* w_g     = (const float*)d_in[3];
    const float* w_mask  = (const float*)d_in[4];
    float* out = (float*)d_out;

    char* ws = (char*)d_ws;
    unsigned short* phiT   = (unsigned short*)(ws);              //  4 MB
    unsigned short* thetaT = (unsigned short*)(ws + 4194304);    //  4 MB
    unsigned short* gbuf   = (unsigned short*)(ws + 8388608);    //  4 MB
    float*          colsum = (float*)(ws + 12582912);            // 64 KB
    // xT (bf16, prep->proj) and O32 (fp32, colsum->mask) alias: xT dead after k_proj,
    // O32 zeroed inside k_colsum which runs after k_proj.
    unsigned short* xT     = (unsigned short*)(ws + 12648448);   //  8 MB
    float*          O32    = (float*)(ws + 12648448);
    unsigned short* Wp     = (unsigned short*)(ws + 21037056);   // 64 KB
    unsigned short* Wt     = (unsigned short*)(ws + 21102592);   // 64 KB
    unsigned short* Wg     = (unsigned short*)(ws + 21168128);   // 64 KB
    unsigned short* Wm     = (unsigned short*)(ws + 21233664);   // 64 KB
    // total ws use: 21,299,200 bytes

    k_prep_w <<<dim3(32),        256, 0, stream>>>(w_phi, w_theta, w_g, w_mask, Wp, Wt, Wg, Wm);
    k_prep_x <<<dim3(64, 4, 4),  256, 0, stream>>>(x, xT, colsum);
    k_proj   <<<dim3(64, 3, 4),  256, 0, stream>>>(Wp, Wt, Wg, xT, phiT, thetaT, gbuf);
    k_colsum <<<dim3(32, 8, 4),  256, 0, stream>>>(thetaT, phiT, colsum, O32);
    k_scale_g<<<dim3(1024),      256, 0, stream>>>(gbuf, colsum);
    k_attn   <<<dim3(64, 2, 4),  256, 0, stream>>>(thetaT, phiT, gbuf, O32);
    k_mask   <<<dim3(64, 2, 4),  256, 0, stream>>>(Wm, O32, x, out);
}